// Round 9
// baseline (308.345 us; speedup 1.0000x reference)
//
#include <hip/hip_runtime.h>
#include <hip/hip_bf16.h>
#include <math.h>
#include <float.h>

#ifndef M_PI
#define M_PI 3.14159265358979323846
#endif

// Problem constants
#define NBANDS 160      // B*NB = 32*5
#define RR 96           // rows per band
#define TT 2048         // time samples
#define NTRIL 4560      // 96*95/2
#define A_ELEMS ((size_t)NBANDS * RR * RR)
#define NBIN 8192
#define MAXCAND 512
#define BKS 64          // K per stage
#define KSPLIT 4        // K-chunks per band (gram parallelism)
#define KCH (TT / KSPLIT)        // 512
#define GSTAGES (KCH / BKS)      // 8
// LDS row pitch (bf16): 76 => b64 accesses bank-uniform (round-7 verified: -20us)
#define GPITCH 76
#define GRAM_BLK 384    // gram kernel: 6 waves, 2x3 tile grid (round-7 proven)
#define FIN_BLK 256     // finalize kernel: 4 waves

// XOR bank swizzle for the FFT kernel
#define PHI(L) ((L) ^ (((L) >> 5) & 31))

typedef float  f32x4  __attribute__((ext_vector_type(4)));
typedef __bf16 bf16x8 __attribute__((ext_vector_type(8)));
typedef __bf16 bf16x4 __attribute__((ext_vector_type(4)));

// ---------- block reductions (any blockDim multiple of 64) ----------
__device__ inline void blockReduceSum4(double v0, double v1, double v2, double v3,
                                       double* sred, double out[4]) {
    for (int off = 32; off > 0; off >>= 1) {
        v0 += __shfl_down(v0, off, 64);
        v1 += __shfl_down(v1, off, 64);
        v2 += __shfl_down(v2, off, 64);
        v3 += __shfl_down(v3, off, 64);
    }
    int lane = threadIdx.x & 63, wid = threadIdx.x >> 6;
    int nw = blockDim.x >> 6;
    if (lane == 0) {
        sred[wid * 4 + 0] = v0; sred[wid * 4 + 1] = v1;
        sred[wid * 4 + 2] = v2; sred[wid * 4 + 3] = v3;
    }
    __syncthreads();
    if (threadIdx.x < 4) {
        double r = sred[threadIdx.x];
        for (int w = 1; w < nw; w++) r += sred[w * 4 + threadIdx.x];
        sred[nw * 4 + threadIdx.x] = r;
    }
    __syncthreads();
    out[0] = sred[nw * 4 + 0]; out[1] = sred[nw * 4 + 1];
    out[2] = sred[nw * 4 + 2]; out[3] = sred[nw * 4 + 3];
    __syncthreads();
}

__device__ inline void blockReduceSum2(double v0, double v1,
                                       double* sred, double out[2]) {
    for (int off = 32; off > 0; off >>= 1) {
        v0 += __shfl_down(v0, off, 64);
        v1 += __shfl_down(v1, off, 64);
    }
    int lane = threadIdx.x & 63, wid = threadIdx.x >> 6;
    int nw = blockDim.x >> 6;
    if (lane == 0) { sred[wid * 2 + 0] = v0; sred[wid * 2 + 1] = v1; }
    __syncthreads();
    if (threadIdx.x < 2) {
        double r = sred[threadIdx.x];
        for (int w = 1; w < nw; w++) r += sred[w * 2 + threadIdx.x];
        sred[nw * 2 + threadIdx.x] = r;
    }
    __syncthreads();
    out[0] = sred[nw * 2 + 0]; out[1] = sred[nw * 2 + 1];
    __syncthreads();
}

__device__ inline void blockReduceMax2(double v0, double v1,
                                       double* sred, double out[2]) {
    for (int off = 32; off > 0; off >>= 1) {
        v0 = fmax(v0, __shfl_down(v0, off, 64));
        v1 = fmax(v1, __shfl_down(v1, off, 64));
    }
    int lane = threadIdx.x & 63, wid = threadIdx.x >> 6;
    int nw = blockDim.x >> 6;
    if (lane == 0) { sred[wid * 2 + 0] = v0; sred[wid * 2 + 1] = v1; }
    __syncthreads();
    if (threadIdx.x < 2) {
        double r = sred[threadIdx.x];
        for (int w = 1; w < nw; w++) r = fmax(r, sred[w * 2 + threadIdx.x]);
        sred[nw * 2 + threadIdx.x] = r;
    }
    __syncthreads();
    out[0] = sred[nw * 2 + 0]; out[1] = sred[nw * 2 + 1];
    __syncthreads();
}

// ---------- K0: twiddle table  tw[k] = exp(-2*pi*i*k/2048), k<1024 (fp32) ----------
__global__ void twiddle_kernel(float* tw) {
    int k = blockIdx.x * blockDim.x + threadIdx.x;
    if (k < 1024) {
        double ang = -2.0 * M_PI * (double)k / 2048.0;
        tw[2 * k]     = (float)cos(ang);
        tw[2 * k + 1] = (float)sin(ang);
    }
}

// DIT butterfly on register pair (r1, r2) with twiddle (WR, WI)
#define BFLY(r1, r2, WR, WI) do { \
    float _wr = (WR), _wi = (WI); \
    float _tr = _wr * yr[r2] - _wi * yi[r2]; \
    float _ti = _wr * yi[r2] + _wi * yr[r2]; \
    yr[r2] = yr[r1] - _tr; yi[r2] = yi[r1] - _ti; \
    yr[r1] += _tr; yi[r1] += _ti; } while (0)

// ---------- K1: per-row stats + fp32 register radix-8 FFT entropy ----------
// Proven 2-rows/block structure (~93 us): packed re/im, 16.9 KB LDS, f32
// per-thread stats, batched reductions, __logf, float2 twiddles.
__global__ __launch_bounds__(256) void rowstat_fft_kernel(
    const float* __restrict__ wc, const float* __restrict__ tw,
    double* __restrict__ rowstats)
{
    __shared__ float re[TT];
    __shared__ float im[TT];
    __shared__ double sred[32];
    __shared__ float bcast[4];

    int t = threadIdx.x;
    int g0 = blockIdx.x * 2;
    int g1 = g0 + 1;

    int band = g0 / RR, r0 = g0 % RR;
    int b = band / 5, nb = band % 5;
    size_t base0 = ((size_t)(b * RR + r0) * 5 + nb) * TT;
    size_t base1 = base0 + (size_t)5 * TT;
    const float2* twv = (const float2*)tw;

    float s0 = 0.f, s1 = 0.f, q0 = 0.f, q1 = 0.f, m0 = 0.f, m1 = 0.f;
#pragma unroll
    for (int c = 0; c < 8; c++) {
        int i = t + c * 256;
        float af = wc[base0 + i];
        float bf = wc[base1 + i];
        int P = PHI(i);
        re[P] = af; im[P] = bf;
        s0 += af; s1 += bf;
        q0 = fmaf(af, af, q0); q1 = fmaf(bf, bf, q1);
        m0 = fmaxf(m0, fabsf(af)); m1 = fmaxf(m1, fabsf(bf));
    }
    __syncthreads();

    double S4[4], M2[2];
    blockReduceSum4((double)s0, (double)s1, (double)q0, (double)q1, sred, S4);
    blockReduceMax2((double)m0, (double)m1, sred, M2);
    double SUM0 = S4[0], SUM1 = S4[1], SQ0 = S4[2], SQ1 = S4[3];
    double MX0 = M2[0], MX1 = M2[1];

    float yr[8], yi[8];

#pragma unroll
    for (int j = 0; j < 8; j++) {
        int p = 8 * t + j;
        int L = (int)(__brev((unsigned)p) >> 21);
        int P = PHI(L);
        yr[j] = re[P]; yi[j] = im[P];
    }

    const float RC = 0.70710678f;
    BFLY(0, 1, 1.0f, 0.0f); BFLY(2, 3, 1.0f, 0.0f);
    BFLY(4, 5, 1.0f, 0.0f); BFLY(6, 7, 1.0f, 0.0f);
    BFLY(0, 2, 1.0f, 0.0f); BFLY(1, 3, 0.0f, -1.0f);
    BFLY(4, 6, 1.0f, 0.0f); BFLY(5, 7, 0.0f, -1.0f);
    BFLY(0, 4, 1.0f, 0.0f); BFLY(1, 5, RC, -RC);
    BFLY(2, 6, 0.0f, -1.0f); BFLY(3, 7, -RC, -RC);

    __syncthreads();
#pragma unroll
    for (int j = 0; j < 8; j++) {
        int P = PHI(8 * t + j);
        re[P] = yr[j]; im[P] = yi[j];
    }
    __syncthreads();
    int oo = t & 7;
    int bb64 = 4 * ((t >> 3) & 7) + (t >> 6);
#pragma unroll
    for (int k = 0; k < 8; k++) {
        int P = PHI(64 * bb64 + 8 * k + oo);
        yr[k] = re[P]; yi[k] = im[P];
    }

    {
        float2 w0 = twv[oo << 7];
        BFLY(0, 1, w0.x, w0.y); BFLY(2, 3, w0.x, w0.y);
        BFLY(4, 5, w0.x, w0.y); BFLY(6, 7, w0.x, w0.y);
        float2 wa = twv[oo << 6];
        float2 wb = twv[(oo + 8) << 6];
        BFLY(0, 2, wa.x, wa.y); BFLY(1, 3, wb.x, wb.y);
        BFLY(4, 6, wa.x, wa.y); BFLY(5, 7, wb.x, wb.y);
        float2 wc0 = twv[oo << 5], wc1 = twv[(oo + 8) << 5];
        float2 wc2 = twv[(oo + 16) << 5], wc3 = twv[(oo + 24) << 5];
        BFLY(0, 4, wc0.x, wc0.y);
        BFLY(1, 5, wc1.x, wc1.y);
        BFLY(2, 6, wc2.x, wc2.y);
        BFLY(3, 7, wc3.x, wc3.y);
    }

    __syncthreads();
#pragma unroll
    for (int k = 0; k < 8; k++) {
        int P = PHI(64 * bb64 + 8 * k + oo);
        re[P] = yr[k]; im[P] = yi[k];
    }
    __syncthreads();
    int O3 = t & 63, Wq = t >> 6;
#pragma unroll
    for (int s = 0; s < 2; s++) {
        int B3 = Wq + 4 * s;
#pragma unroll
        for (int k = 0; k < 4; k++) {
            int P = PHI(256 * B3 + 64 * k + O3);
            yr[4 * s + k] = re[P]; yi[4 * s + k] = im[P];
        }
    }

    {
        float2 w0 = twv[O3 << 4];
        float2 wa = twv[O3 << 3];
        float2 wb = twv[(O3 + 64) << 3];
        BFLY(0, 1, w0.x, w0.y); BFLY(2, 3, w0.x, w0.y);
        BFLY(4, 5, w0.x, w0.y); BFLY(6, 7, w0.x, w0.y);
        BFLY(0, 2, wa.x, wa.y); BFLY(1, 3, wb.x, wb.y);
        BFLY(4, 6, wa.x, wa.y); BFLY(5, 7, wb.x, wb.y);
    }

    __syncthreads();
#pragma unroll
    for (int s = 0; s < 2; s++) {
        int B3 = Wq + 4 * s;
#pragma unroll
        for (int k = 0; k < 4; k++) {
            int P = PHI(256 * B3 + 64 * k + O3);
            re[P] = yr[4 * s + k]; im[P] = yi[4 * s + k];
        }
    }
    __syncthreads();
#pragma unroll
    for (int k = 0; k < 8; k++) {
        int P = PHI(256 * k + t);
        yr[k] = re[P]; yi[k] = im[P];
    }

    {
        float2 w0 = twv[t << 2];
        float2 wa = twv[t << 1];
        float2 wb = twv[(t + 256) << 1];
        BFLY(0, 1, w0.x, w0.y); BFLY(2, 3, w0.x, w0.y);
        BFLY(4, 5, w0.x, w0.y); BFLY(6, 7, w0.x, w0.y);
        BFLY(0, 2, wa.x, wa.y); BFLY(1, 3, wb.x, wb.y);
        BFLY(4, 6, wa.x, wa.y); BFLY(5, 7, wb.x, wb.y);
        float2 wf0 = twv[t], wf1 = twv[t + 256];
        float2 wf2 = twv[t + 512], wf3 = twv[t + 768];
        BFLY(0, 4, wf0.x, wf0.y);
        BFLY(1, 5, wf1.x, wf1.y);
        BFLY(2, 6, wf2.x, wf2.y);
        BFLY(3, 7, wf3.x, wf3.y);
    }

    __syncthreads();
#pragma unroll
    for (int k = 0; k < 8; k++) {
        int P = PHI(256 * k + t);
        re[P] = yr[k]; im[P] = yi[k];
    }
    __syncthreads();

    float psa[8], psb[8];
#pragma unroll
    for (int k = 0; k < 8; k++) {
        int q = (2048 - t - 256 * k) & 2047;
        int P = PHI(q);
        float prr = re[P], pii = im[P];
        float sr = yr[k] + prr, di = yi[k] - pii;
        float si = yi[k] + pii, dr = yr[k] - prr;
        psa[k] = 0.25f * (sr * sr + di * di);
        psb[k] = 0.25f * (si * si + dr * dr);
    }

    float la = 0.f, lb = 0.f;
#pragma unroll
    for (int k = 0; k < 8; k++) { la += psa[k]; lb += psb[k]; }
    double SS[2];
    blockReduceSum2((double)la, (double)lb, sred, SS);
    double SAall = SS[0], SBall = SS[1];
    if (t == 0) {
        bcast[0] = psa[0]; bcast[1] = psa[4];
        bcast[2] = psb[0]; bcast[3] = psb[4];
    }
    __syncthreads();
    double Sa = 0.5 * (SAall + (double)bcast[0] - (double)bcast[1]);
    double Sb = 0.5 * (SBall + (double)bcast[2] - (double)bcast[3]);
    if (Sa == 0.0) Sa = 1.0;
    if (Sb == 0.0) Sb = 1.0;
    float invSa = (float)(1.0 / Sa), invSb = (float)(1.0 / Sb);

    float ea = 0.f, eb = 0.f;
#pragma unroll
    for (int k = 0; k < 8; k++) {
        float pa = psa[k] * invSa;
        float pb = psb[k] * invSb;
        ea += pa * __logf(pa + 1e-10f);
        eb += pb * __logf(pb + 1e-10f);
    }
    double EE[2];
    blockReduceSum2((double)ea, (double)eb, sred, EE);
    double EAall = EE[0], EBall = EE[1];

    if (t == 0) {
        float pa0 = psa[0] * invSa, pa4 = psa[4] * invSa;
        float pb0 = psb[0] * invSb, pb4 = psb[4] * invSb;
        double TA = 0.5 * (EAall + (double)(pa0 * __logf(pa0 + 1e-10f))
                                 - (double)(pa4 * __logf(pa4 + 1e-10f)));
        double TB = 0.5 * (EBall + (double)(pb0 * __logf(pb0 + 1e-10f))
                                 - (double)(pb4 * __logf(pb4 + 1e-10f)));
        double mean0 = SUM0 / (double)TT;
        double mean1 = SUM1 / (double)TT;
        double nsq0 = SQ0 - (double)TT * mean0 * mean0; if (nsq0 < 0) nsq0 = 0;
        double nsq1 = SQ1 - (double)TT * mean1 * mean1; if (nsq1 < 0) nsq1 = 0;
        double* w0 = rowstats + (size_t)g0 * 6;
        double* w1 = rowstats + (size_t)g1 * 6;
        double n0 = sqrt(nsq0), n1 = sqrt(nsq1);
        w0[0] = mean0; w0[1] = (n0 == 0.0 ? 1.0 : n0); w0[2] = sqrt(nsq0 / 2047.0);
        w0[3] = SQ0;   w0[4] = MX0;                    w0[5] = -TA;
        w1[0] = mean1; w1[1] = (n1 == 0.0 ? 1.0 : n1); w1[2] = sqrt(nsq1 / 2047.0);
        w1[3] = SQ1;   w1[4] = MX1;                    w1[5] = -TB;
    }
}

// fp32 -> hi/lo bf16 split into LDS staging buffer BUF
#define CVW(BUF, v, row, c4) do { \
    __bf16 _h0 = (__bf16)v.x, _h1 = (__bf16)v.y, _h2 = (__bf16)v.z, _h3 = (__bf16)v.w; \
    __bf16 _l0 = (__bf16)(v.x - (float)_h0), _l1 = (__bf16)(v.y - (float)_h1); \
    __bf16 _l2 = (__bf16)(v.z - (float)_h2), _l3 = (__bf16)(v.w - (float)_h3); \
    *(bf16x4*)&sh_hi[BUF][row][(c4) * 4] = (bf16x4){_h0, _h1, _h2, _h3}; \
    *(bf16x4*)&sh_lo[BUF][row][(c4) * 4] = (bf16x4){_l0, _l1, _l2, _l3}; } while (0)

// load a bf16x8 fragment as two ds_read_b64
#define LDFRAG(dst, arr, BUF, row, ko) do { \
    bf16x4 _f0 = *(const bf16x4*)&arr[BUF][row][ko]; \
    bf16x4 _f1 = *(const bf16x4*)&arr[BUF][row][(ko) + 4]; \
    dst = (bf16x8){_f0[0], _f0[1], _f0[2], _f0[3], _f1[0], _f1[1], _f1[2], _f1[3]}; } while (0)

// ---------- K2a: gram partials, K-split 4-way ----------
// grid = NBANDS*KSPLIT blocks of 384 thr (6 waves, 2x3 tile grid: wave owns
// 32 rows x 48 cols — round-7 proven geometry). Each block K-loops its 512-
// sample chunk in 8 double-buffered stages and stores its 96x96 partial to
// workspace. 640 blocks -> 2 blocks/CU (LDS 58.4KB) -> 12 waves/CU, 4x the
// latency hiding of the fused single-block-per-band version.
__global__ __launch_bounds__(GRAM_BLK) void gram_part_kernel(
    const float* __restrict__ wc, float* __restrict__ Gpart)
{
    __shared__ __attribute__((aligned(16))) __bf16 sh_hi[2][RR][GPITCH];
    __shared__ __attribute__((aligned(16))) __bf16 sh_lo[2][RR][GPITCH];

    int bid = blockIdx.x, t = threadIdx.x;
    int band = bid / KSPLIT, kc = bid % KSPLIT;
    int b = band / 5, nb = band % 5;
    size_t bandbase = ((size_t)b * RR * 5 + nb) * TT + (size_t)kc * KCH;

    int wave = t >> 6, lane = t & 63;
    int m16 = lane & 15, quad = lane >> 4;
    int wr = wave >> 1;          // 0..2  (row block of 32)
    int wcx = wave & 1;          // 0..1  (col block of 48)

    // staging slots: gid = t + i*384 over 1536 = 96 rows x 16 float4
    int row0 = t >> 4,           c40 = t & 15;
    int row1 = (t + 384) >> 4,   c41 = (t + 384) & 15;
    int row2 = (t + 768) >> 4,   c42 = (t + 768) & 15;
    int row3 = (t + 1152) >> 4,  c43 = (t + 1152) & 15;
    const float* p0 = wc + bandbase + (size_t)row0 * (5 * TT) + c40 * 4;
    const float* p1 = wc + bandbase + (size_t)row1 * (5 * TT) + c41 * 4;
    const float* p2 = wc + bandbase + (size_t)row2 * (5 * TT) + c42 * 4;
    const float* p3 = wc + bandbase + (size_t)row3 * (5 * TT) + c43 * 4;

    f32x4 acc[2][3];
#pragma unroll
    for (int rs = 0; rs < 2; rs++)
#pragma unroll
        for (int cs = 0; cs < 3; cs++) acc[rs][cs] = (f32x4){0.f, 0.f, 0.f, 0.f};

    {
        float4 v0 = *(const float4*)(p0);
        float4 v1 = *(const float4*)(p1);
        float4 v2 = *(const float4*)(p2);
        float4 v3 = *(const float4*)(p3);
        CVW(0, v0, row0, c40); CVW(0, v1, row1, c41);
        CVW(0, v2, row2, c42); CVW(0, v3, row3, c43);
    }
    __syncthreads();

    for (int st = 0; st < GSTAGES; st++) {
        int cur = st & 1;
        float4 q0, q1, q2, q3;
        bool more = (st + 1 < GSTAGES);
        if (more) {
            int k0 = (st + 1) * BKS;
            q0 = *(const float4*)(p0 + k0);
            q1 = *(const float4*)(p1 + k0);
            q2 = *(const float4*)(p2 + k0);
            q3 = *(const float4*)(p3 + k0);
        }
#pragma unroll
        for (int ks = 0; ks < BKS / 32; ks++) {
            int ko = ks * 32 + quad * 8;
            bf16x8 ah[2], al[2];
#pragma unroll
            for (int rs = 0; rs < 2; rs++) {
                int ar = (wr * 2 + rs) * 16 + m16;
                LDFRAG(ah[rs], sh_hi, cur, ar, ko);
                LDFRAG(al[rs], sh_lo, cur, ar, ko);
            }
#pragma unroll
            for (int cs = 0; cs < 3; cs++) {
                int br = (wcx * 3 + cs) * 16 + m16;
                bf16x8 bh, bl;
                LDFRAG(bh, sh_hi, cur, br, ko);
                LDFRAG(bl, sh_lo, cur, br, ko);
#pragma unroll
                for (int rs = 0; rs < 2; rs++) {
                    acc[rs][cs] = __builtin_amdgcn_mfma_f32_16x16x32_bf16(ah[rs], bh, acc[rs][cs], 0, 0, 0);
                    acc[rs][cs] = __builtin_amdgcn_mfma_f32_16x16x32_bf16(ah[rs], bl, acc[rs][cs], 0, 0, 0);
                    acc[rs][cs] = __builtin_amdgcn_mfma_f32_16x16x32_bf16(al[rs], bh, acc[rs][cs], 0, 0, 0);
                }
            }
        }
        if (more) {
            int nxt = cur ^ 1;
            CVW(nxt, q0, row0, c40); CVW(nxt, q1, row1, c41);
            CVW(nxt, q2, row2, c42); CVW(nxt, q3, row3, c43);
        }
        __syncthreads();
    }

    float* Gp = Gpart + (size_t)bid * (RR * RR);
#pragma unroll
    for (int rs = 0; rs < 2; rs++) {
#pragma unroll
        for (int cs = 0; cs < 3; cs++) {
#pragma unroll
            for (int r = 0; r < 4; r++) {
                int grow = (wr * 2 + rs) * 16 + quad * 4 + r;
                int gcol = (wcx * 3 + cs) * 16 + m16;
                Gp[grow * RR + gcol] = acc[rs][cs][r];
            }
        }
    }
}

// ---------- K2b: per-band finalize ----------
// 160 blocks x 256 thr. Sum KSPLIT partials -> normalize -> Cs (LDS) +
// histogram -> parallel quantile select -> parallel rank selection -> masked
// A write -> ballot bitmask graph props -> MLP -> F. ~78KB LDS, 2 blocks/CU.
__global__ __launch_bounds__(FIN_BLK) void band_finalize_kernel(
    const float* __restrict__ Gpart, const double* __restrict__ rowstats,
    const int* __restrict__ community,
    const float* __restrict__ W1, const float* __restrict__ b1,
    const float* __restrict__ W2, const float* __restrict__ b2,
    float* __restrict__ A_out, float* __restrict__ F_out)
{
    __shared__ float Cs[RR][RR];               // 36 KB
    __shared__ int hist[NBIN];                 // 32 KB
    __shared__ int chunkv[256];
    __shared__ int pchunk[256];
    __shared__ int gpre_s[64];
    __shared__ float cand[MAXCAND];
    __shared__ int ctrl[8];
    __shared__ float selv[2];
    __shared__ double mean_s[RR], inv_s[RR];
    __shared__ int comm_s[RR];
    __shared__ unsigned long long msk[RR][2];
    __shared__ int deg[RR];
    __shared__ double sred[32];
    __shared__ double feat[11];
    __shared__ double hmlp[32];
    __shared__ double thr_s;

    int band = blockIdx.x, t = threadIdx.x;
    const double* rsb = rowstats + (size_t)band * RR * 6;

    if (t < RR) {
        mean_s[t] = rsb[t * 6 + 0];
        inv_s[t]  = 1.0 / rsb[t * 6 + 1];
        comm_s[t] = community[t];
    }
    for (int i = t; i < NBIN; i += FIN_BLK) hist[i] = 0;
    if (t == 0) ctrl[3] = 0;
    __syncthreads();

    // sum partials + normalize into Cs, histogram tril on the fly
    const float* Pb = Gpart + (size_t)band * KSPLIT * (RR * RR);
    for (int idx = t; idx < RR * RR; idx += FIN_BLK) {
        float g = 0.f;
#pragma unroll
        for (int c = 0; c < KSPLIT; c++) g += Pb[(size_t)c * (RR * RR) + idx];
        int i = idx / RR, j = idx % RR;
        double cd = ((double)g - (double)TT * mean_s[i] * mean_s[j])
                    * (inv_s[i] * inv_s[j]);
        if (i == j) cd = 0.0;
        float cf = (float)cd;
        Cs[i][j] = cf;
        if (j < i) {
            float val = fabsf(cf);
            int bin = (int)(val * (float)NBIN);
            bin = bin > (NBIN - 1) ? (NBIN - 1) : bin;
            atomicAdd(&hist[bin], 1);
        }
    }
    __syncthreads();

    // ---- parallel quantile select: ranks R0=3647, R1=3648 ----
    {
        int cs = 0;
#pragma unroll
        for (int i = 0; i < NBIN / 256; i++) cs += hist[t * (NBIN / 256) + i];
        chunkv[t] = cs;
    }
    __syncthreads();
    if (t < 64) {
        int s4 = chunkv[4 * t] + chunkv[4 * t + 1] + chunkv[4 * t + 2] + chunkv[4 * t + 3];
        int inc = s4;
        for (int d = 1; d < 64; d <<= 1) {
            int u = __shfl_up(inc, d, 64);
            if (t >= d) inc += u;
        }
        gpre_s[t] = inc - s4;               // exclusive prefix of 4-chunk groups
    }
    __syncthreads();
    {
        int base = gpre_s[t >> 2];
        for (int j = (t & ~3); j < t; j++) base += chunkv[j];
        pchunk[t] = base;                    // exclusive prefix of chunk t
    }
    __syncthreads();
    {
        int lo = pchunk[t], hi2 = lo + chunkv[t];
        if (lo <= 3647 && 3647 < hi2) ctrl[4] = t;
        if (lo <= 3648 && 3648 < hi2) ctrl[5] = t;
    }
    __syncthreads();
    {
        int c0 = ctrl[4], c1 = ctrl[5];
        if (t < 32) {
            int binb = c0 * 32;
            int pre = pchunk[c0];
            for (int j = 0; j < t; j++) pre += hist[binb + j];
            int cnt = hist[binb + t];
            if (pre <= 3647 && 3647 < pre + cnt) { ctrl[0] = binb + t; ctrl[2] = pre; }
        } else if (t < 64) {
            int tt2 = t - 32;
            int binb = c1 * 32;
            int pre = pchunk[c1];
            for (int j = 0; j < tt2; j++) pre += hist[binb + j];
            int cnt = hist[binb + tt2];
            if (pre <= 3648 && 3648 < pre + cnt) ctrl[1] = binb + tt2;
        }
    }
    __syncthreads();

    int B0 = ctrl[0], B1 = ctrl[1];
    for (int idx = t; idx < RR * RR; idx += FIN_BLK) {
        int i = idx / RR, j = idx % RR;
        if (j < i) {
            float val = fabsf(Cs[i][j]);
            int bin = (int)(val * (float)NBIN);
            bin = bin > (NBIN - 1) ? (NBIN - 1) : bin;
            if (bin >= B0 && bin <= B1) {
                int k = atomicAdd(&ctrl[3], 1);
                if (k < MAXCAND) cand[k] = val;
            }
        }
    }
    __syncthreads();

    // parallel rank selection (unique total order via (value, index) tie-break)
    {
        int n = ctrl[3]; if (n > MAXCAND) n = MAXCAND;
        int r0l = 3647 - ctrl[2];
        int r1l = 3648 - ctrl[2];
        for (int i = t; i < n; i += FIN_BLK) {
            float v = cand[i];
            int rank = 0;
            for (int j = 0; j < n; j++) {
                float u = cand[j];
                rank += (u < v || (u == v && j < i)) ? 1 : 0;
            }
            if (rank == r0l) selv[0] = v;
            if (rank == r1l) selv[1] = v;
        }
    }
    __syncthreads();
    if (t == 0) {
        double v0 = (double)selv[0], v1 = (double)selv[1];
        thr_s = v0 + 0.2 * (v1 - v0);       // pos = 0.8*(4560-1) = 3647.2
    }
    __syncthreads();
    double thr = thr_s;

    // masked A write (single pass, coalesced)
    float* Ab = A_out + (size_t)band * (RR * RR);
    for (int idx = t; idx < RR * RR; idx += FIN_BLK) {
        float cf = Cs[idx / RR][idx % RR];
        bool keep = ((double)fabsf(cf) >= thr);
        Ab[idx] = keep ? cf : 0.f;
    }

    // adjacency bitmasks via ballot: wave w handles rows w, w+4, ...
    int wave = t >> 6, lane = t & 63;
    for (int i = wave; i < RR; i += 4) {
        float vlo = Cs[i][lane];
        bool klo = ((double)fabsf(vlo) >= thr) && (vlo != 0.f);
        unsigned long long blo = __ballot(klo);
        float vhi = Cs[i][64 + (lane & 31)];
        bool khi = (lane < 32) && ((double)fabsf(vhi) >= thr) && (vhi != 0.f);
        unsigned long long bhi = __ballot(khi) & 0xffffffffull;
        if (lane == 0) {
            msk[i][0] = blo; msk[i][1] = bhi;
            deg[i] = __popcll(blo) + __popcll(bhi);
        }
    }
    __syncthreads();

    double triord = 0, ein = 0, expin = 0;
    for (int idx = t; idx < RR * RR; idx += FIN_BLK) {
        int i = idx / RR, j = idx % RR;
        unsigned long long mi0 = msk[i][0], mi1 = msk[i][1];
        bool bij = (((j < 64) ? (mi0 >> j) : (mi1 >> (j - 64))) & 1ull) != 0;
        if (bij)
            triord += (double)(__popcll(mi0 & msk[j][0]) +
                               __popcll(mi1 & msk[j][1]));
        if (i != j && comm_s[i] == comm_s[j]) {
            ein += bij ? 1.0 : 0.0;
            expin += (double)deg[i] * (double)deg[j];
        }
    }
    double dv = (t < RR) ? (double)deg[t] : 0.0;
    double R1v[4], R2v[4], R3v[2];
    blockReduceSum4(triord, ein, expin, dv, sred, R1v);
    blockReduceSum4((t < RR) ? dv * (dv - 1.0) : 0.0,
                    (t < RR) ? rsb[t * 6 + 0] : 0.0,
                    (t < RR) ? rsb[t * 6 + 2] : 0.0,
                    (t < RR) ? rsb[t * 6 + 3] : 0.0, sred, R2v);
    blockReduceSum2((t < RR) ? rsb[t * 6 + 4] : 0.0,
                    (t < RR) ? rsb[t * 6 + 5] : 0.0, sred, R3v);
    double TRI = R1v[0], EIN = R1v[1], EXPIN = R1v[2], DEGS = R1v[3];
    double POSS2 = R2v[0], N0 = R2v[1], N1 = R2v[2], N2 = R2v[3];
    double N3 = R3v[0], N4 = R3v[1];

    if (t == 0) {
        double ne = 0.5 * DEGS;
        feat[0] = N0 / (double)RR;
        feat[1] = N1 / (double)RR;
        feat[2] = N2 / (double)RR;
        feat[3] = N3 / (double)RR;
        feat[4] = N4 / (double)RR;
        feat[5] = ne;
        feat[6] = ne / (double)NTRIL;
        feat[7] = DEGS / (double)RR;
        double tri = TRI / 6.0, poss = POSS2 * 0.5;
        feat[8] = (poss > 0.0) ? tri / poss : 0.0;
        feat[9] = ((double)RR + DEGS) / ((double)RR * (double)(RR - 1));
        double m2 = DEGS;
        feat[10] = (m2 > 0.0) ? (EIN - EXPIN / m2) / m2 : 0.0;
    }
    __syncthreads();

    if (t < 32) {
        double a = (double)b1[t];
        for (int k = 0; k < 11; k++) a += (double)W1[t * 11 + k] * feat[k];
        hmlp[t] = (a > 0.0) ? a : 0.0;
    }
    __syncthreads();
    if (t < 64) {
        double a = (double)b2[t];
        for (int j = 0; j < 32; j++) a += (double)W2[t * 32 + j] * hmlp[j];
        F_out[(size_t)band * 64 + t] = (float)a;
    }
}

extern "C" void kernel_launch(void* const* d_in, const int* in_sizes, int n_in,
                              void* d_out, int out_size, void* d_ws, size_t ws_size,
                              hipStream_t stream) {
    const float* wc        = (const float*)d_in[0];
    // d_in[1] frequency_bands: unused by the reference math
    const int*   community = (const int*)d_in[2];
    const float* W1        = (const float*)d_in[3];
    const float* b1        = (const float*)d_in[4];
    const float* W2        = (const float*)d_in[5];
    const float* b2        = (const float*)d_in[6];

    float* A_out = (float*)d_out;
    float* F_out = A_out + A_ELEMS;

    // workspace: tw @ 0 (8192) | rowstats @ 8192 (737280) | Gpart @ 745472
    //   Gpart = 160*4*9216*4 = 23,592,960 B  (rounds 1-2 ran with 47 MB: fits)
    char* ws = (char*)d_ws;
    float*  tw       = (float*)ws;
    double* rowstats = (double*)(ws + 8192);
    float*  Gpart    = (float*)(ws + 745472);

    hipLaunchKernelGGL(twiddle_kernel, dim3(4), dim3(256), 0, stream, tw);
    hipLaunchKernelGGL(rowstat_fft_kernel, dim3(NBANDS * RR / 2), dim3(256), 0, stream,
                       wc, tw, rowstats);
    hipLaunchKernelGGL(gram_part_kernel, dim3(NBANDS * KSPLIT), dim3(GRAM_BLK), 0, stream,
                       wc, Gpart);
    hipLaunchKernelGGL(band_finalize_kernel, dim3(NBANDS), dim3(FIN_BLK), 0, stream,
                       Gpart, rowstats, community, W1, b1, W2, b2, A_out, F_out);
}

// Round 10
// 286.128 us; speedup vs baseline: 1.0776x; 1.0776x over previous
//
#include <hip/hip_runtime.h>
#include <hip/hip_bf16.h>
#include <math.h>
#include <float.h>

#ifndef M_PI
#define M_PI 3.14159265358979323846
#endif

// Problem constants
#define NBANDS 160      // B*NB = 32*5
#define RR 96           // rows per band
#define TT 2048         // time samples
#define NTRIL 4560      // 96*95/2
#define A_ELEMS ((size_t)NBANDS * RR * RR)
#define NBIN 8192
#define MAXCAND 512
#define BKS 64          // K per stage
#define NST (TT / BKS)  // 32 stages
// LDS row pitch (bf16): 76 => b64 accesses bank-uniform (round-7 verified)
#define GPITCH 76
#define FBLK 512        // fused kernel: 8 waves = 2x2 tile grid x 2-way K-split

// XOR bank swizzle for the FFT kernel
#define PHI(L) ((L) ^ (((L) >> 5) & 31))

typedef float  f32x4  __attribute__((ext_vector_type(4)));
typedef __bf16 bf16x8 __attribute__((ext_vector_type(8)));
typedef __bf16 bf16x4 __attribute__((ext_vector_type(4)));

// ---------- block reductions (any blockDim multiple of 64) ----------
__device__ inline void blockReduceSum4(double v0, double v1, double v2, double v3,
                                       double* sred, double out[4]) {
    for (int off = 32; off > 0; off >>= 1) {
        v0 += __shfl_down(v0, off, 64);
        v1 += __shfl_down(v1, off, 64);
        v2 += __shfl_down(v2, off, 64);
        v3 += __shfl_down(v3, off, 64);
    }
    int lane = threadIdx.x & 63, wid = threadIdx.x >> 6;
    int nw = blockDim.x >> 6;
    if (lane == 0) {
        sred[wid * 4 + 0] = v0; sred[wid * 4 + 1] = v1;
        sred[wid * 4 + 2] = v2; sred[wid * 4 + 3] = v3;
    }
    __syncthreads();
    if (threadIdx.x < 4) {
        double r = sred[threadIdx.x];
        for (int w = 1; w < nw; w++) r += sred[w * 4 + threadIdx.x];
        sred[nw * 4 + threadIdx.x] = r;
    }
    __syncthreads();
    out[0] = sred[nw * 4 + 0]; out[1] = sred[nw * 4 + 1];
    out[2] = sred[nw * 4 + 2]; out[3] = sred[nw * 4 + 3];
    __syncthreads();
}

__device__ inline void blockReduceSum2(double v0, double v1,
                                       double* sred, double out[2]) {
    for (int off = 32; off > 0; off >>= 1) {
        v0 += __shfl_down(v0, off, 64);
        v1 += __shfl_down(v1, off, 64);
    }
    int lane = threadIdx.x & 63, wid = threadIdx.x >> 6;
    int nw = blockDim.x >> 6;
    if (lane == 0) { sred[wid * 2 + 0] = v0; sred[wid * 2 + 1] = v1; }
    __syncthreads();
    if (threadIdx.x < 2) {
        double r = sred[threadIdx.x];
        for (int w = 1; w < nw; w++) r += sred[w * 2 + threadIdx.x];
        sred[nw * 2 + threadIdx.x] = r;
    }
    __syncthreads();
    out[0] = sred[nw * 2 + 0]; out[1] = sred[nw * 2 + 1];
    __syncthreads();
}

__device__ inline void blockReduceMax2(double v0, double v1,
                                       double* sred, double out[2]) {
    for (int off = 32; off > 0; off >>= 1) {
        v0 = fmax(v0, __shfl_down(v0, off, 64));
        v1 = fmax(v1, __shfl_down(v1, off, 64));
    }
    int lane = threadIdx.x & 63, wid = threadIdx.x >> 6;
    int nw = blockDim.x >> 6;
    if (lane == 0) { sred[wid * 2 + 0] = v0; sred[wid * 2 + 1] = v1; }
    __syncthreads();
    if (threadIdx.x < 2) {
        double r = sred[threadIdx.x];
        for (int w = 1; w < nw; w++) r = fmax(r, sred[w * 2 + threadIdx.x]);
        sred[nw * 2 + threadIdx.x] = r;
    }
    __syncthreads();
    out[0] = sred[nw * 2 + 0]; out[1] = sred[nw * 2 + 1];
    __syncthreads();
}

// ---------- K0: twiddle table  tw[k] = exp(-2*pi*i*k/2048), k<1024 (fp32) ----------
__global__ void twiddle_kernel(float* tw) {
    int k = blockIdx.x * blockDim.x + threadIdx.x;
    if (k < 1024) {
        double ang = -2.0 * M_PI * (double)k / 2048.0;
        tw[2 * k]     = (float)cos(ang);
        tw[2 * k + 1] = (float)sin(ang);
    }
}

// DIT butterfly on register pair (r1, r2) with twiddle (WR, WI)
#define BFLY(r1, r2, WR, WI) do { \
    float _wr = (WR), _wi = (WI); \
    float _tr = _wr * yr[r2] - _wi * yi[r2]; \
    float _ti = _wr * yi[r2] + _wi * yr[r2]; \
    yr[r2] = yr[r1] - _tr; yi[r2] = yi[r1] - _ti; \
    yr[r1] += _tr; yi[r1] += _ti; } while (0)

// ---------- K1: per-row stats + fp32 register radix-8 FFT entropy ----------
// Proven 2-rows/block structure (~93 us).
__global__ __launch_bounds__(256) void rowstat_fft_kernel(
    const float* __restrict__ wc, const float* __restrict__ tw,
    double* __restrict__ rowstats)
{
    __shared__ float re[TT];
    __shared__ float im[TT];
    __shared__ double sred[32];
    __shared__ float bcast[4];

    int t = threadIdx.x;
    int g0 = blockIdx.x * 2;
    int g1 = g0 + 1;

    int band = g0 / RR, r0 = g0 % RR;
    int b = band / 5, nb = band % 5;
    size_t base0 = ((size_t)(b * RR + r0) * 5 + nb) * TT;
    size_t base1 = base0 + (size_t)5 * TT;
    const float2* twv = (const float2*)tw;

    float s0 = 0.f, s1 = 0.f, q0 = 0.f, q1 = 0.f, m0 = 0.f, m1 = 0.f;
#pragma unroll
    for (int c = 0; c < 8; c++) {
        int i = t + c * 256;
        float af = wc[base0 + i];
        float bf = wc[base1 + i];
        int P = PHI(i);
        re[P] = af; im[P] = bf;
        s0 += af; s1 += bf;
        q0 = fmaf(af, af, q0); q1 = fmaf(bf, bf, q1);
        m0 = fmaxf(m0, fabsf(af)); m1 = fmaxf(m1, fabsf(bf));
    }
    __syncthreads();

    double S4[4], M2[2];
    blockReduceSum4((double)s0, (double)s1, (double)q0, (double)q1, sred, S4);
    blockReduceMax2((double)m0, (double)m1, sred, M2);
    double SUM0 = S4[0], SUM1 = S4[1], SQ0 = S4[2], SQ1 = S4[3];
    double MX0 = M2[0], MX1 = M2[1];

    float yr[8], yi[8];

#pragma unroll
    for (int j = 0; j < 8; j++) {
        int p = 8 * t + j;
        int L = (int)(__brev((unsigned)p) >> 21);
        int P = PHI(L);
        yr[j] = re[P]; yi[j] = im[P];
    }

    const float RC = 0.70710678f;
    BFLY(0, 1, 1.0f, 0.0f); BFLY(2, 3, 1.0f, 0.0f);
    BFLY(4, 5, 1.0f, 0.0f); BFLY(6, 7, 1.0f, 0.0f);
    BFLY(0, 2, 1.0f, 0.0f); BFLY(1, 3, 0.0f, -1.0f);
    BFLY(4, 6, 1.0f, 0.0f); BFLY(5, 7, 0.0f, -1.0f);
    BFLY(0, 4, 1.0f, 0.0f); BFLY(1, 5, RC, -RC);
    BFLY(2, 6, 0.0f, -1.0f); BFLY(3, 7, -RC, -RC);

    __syncthreads();
#pragma unroll
    for (int j = 0; j < 8; j++) {
        int P = PHI(8 * t + j);
        re[P] = yr[j]; im[P] = yi[j];
    }
    __syncthreads();
    int oo = t & 7;
    int bb64 = 4 * ((t >> 3) & 7) + (t >> 6);
#pragma unroll
    for (int k = 0; k < 8; k++) {
        int P = PHI(64 * bb64 + 8 * k + oo);
        yr[k] = re[P]; yi[k] = im[P];
    }

    {
        float2 w0 = twv[oo << 7];
        BFLY(0, 1, w0.x, w0.y); BFLY(2, 3, w0.x, w0.y);
        BFLY(4, 5, w0.x, w0.y); BFLY(6, 7, w0.x, w0.y);
        float2 wa = twv[oo << 6];
        float2 wb = twv[(oo + 8) << 6];
        BFLY(0, 2, wa.x, wa.y); BFLY(1, 3, wb.x, wb.y);
        BFLY(4, 6, wa.x, wa.y); BFLY(5, 7, wb.x, wb.y);
        float2 wc0 = twv[oo << 5], wc1 = twv[(oo + 8) << 5];
        float2 wc2 = twv[(oo + 16) << 5], wc3 = twv[(oo + 24) << 5];
        BFLY(0, 4, wc0.x, wc0.y);
        BFLY(1, 5, wc1.x, wc1.y);
        BFLY(2, 6, wc2.x, wc2.y);
        BFLY(3, 7, wc3.x, wc3.y);
    }

    __syncthreads();
#pragma unroll
    for (int k = 0; k < 8; k++) {
        int P = PHI(64 * bb64 + 8 * k + oo);
        re[P] = yr[k]; im[P] = yi[k];
    }
    __syncthreads();
    int O3 = t & 63, Wq = t >> 6;
#pragma unroll
    for (int s = 0; s < 2; s++) {
        int B3 = Wq + 4 * s;
#pragma unroll
        for (int k = 0; k < 4; k++) {
            int P = PHI(256 * B3 + 64 * k + O3);
            yr[4 * s + k] = re[P]; yi[4 * s + k] = im[P];
        }
    }

    {
        float2 w0 = twv[O3 << 4];
        float2 wa = twv[O3 << 3];
        float2 wb = twv[(O3 + 64) << 3];
        BFLY(0, 1, w0.x, w0.y); BFLY(2, 3, w0.x, w0.y);
        BFLY(4, 5, w0.x, w0.y); BFLY(6, 7, w0.x, w0.y);
        BFLY(0, 2, wa.x, wa.y); BFLY(1, 3, wb.x, wb.y);
        BFLY(4, 6, wa.x, wa.y); BFLY(5, 7, wb.x, wb.y);
    }

    __syncthreads();
#pragma unroll
    for (int s = 0; s < 2; s++) {
        int B3 = Wq + 4 * s;
#pragma unroll
        for (int k = 0; k < 4; k++) {
            int P = PHI(256 * B3 + 64 * k + O3);
            re[P] = yr[4 * s + k]; im[P] = yi[4 * s + k];
        }
    }
    __syncthreads();
#pragma unroll
    for (int k = 0; k < 8; k++) {
        int P = PHI(256 * k + t);
        yr[k] = re[P]; yi[k] = im[P];
    }

    {
        float2 w0 = twv[t << 2];
        float2 wa = twv[t << 1];
        float2 wb = twv[(t + 256) << 1];
        BFLY(0, 1, w0.x, w0.y); BFLY(2, 3, w0.x, w0.y);
        BFLY(4, 5, w0.x, w0.y); BFLY(6, 7, w0.x, w0.y);
        BFLY(0, 2, wa.x, wa.y); BFLY(1, 3, wb.x, wb.y);
        BFLY(4, 6, wa.x, wa.y); BFLY(5, 7, wb.x, wb.y);
        float2 wf0 = twv[t], wf1 = twv[t + 256];
        float2 wf2 = twv[t + 512], wf3 = twv[t + 768];
        BFLY(0, 4, wf0.x, wf0.y);
        BFLY(1, 5, wf1.x, wf1.y);
        BFLY(2, 6, wf2.x, wf2.y);
        BFLY(3, 7, wf3.x, wf3.y);
    }

    __syncthreads();
#pragma unroll
    for (int k = 0; k < 8; k++) {
        int P = PHI(256 * k + t);
        re[P] = yr[k]; im[P] = yi[k];
    }
    __syncthreads();

    float psa[8], psb[8];
#pragma unroll
    for (int k = 0; k < 8; k++) {
        int q = (2048 - t - 256 * k) & 2047;
        int P = PHI(q);
        float prr = re[P], pii = im[P];
        float sr = yr[k] + prr, di = yi[k] - pii;
        float si = yi[k] + pii, dr = yr[k] - prr;
        psa[k] = 0.25f * (sr * sr + di * di);
        psb[k] = 0.25f * (si * si + dr * dr);
    }

    float la = 0.f, lb = 0.f;
#pragma unroll
    for (int k = 0; k < 8; k++) { la += psa[k]; lb += psb[k]; }
    double SS[2];
    blockReduceSum2((double)la, (double)lb, sred, SS);
    double SAall = SS[0], SBall = SS[1];
    if (t == 0) {
        bcast[0] = psa[0]; bcast[1] = psa[4];
        bcast[2] = psb[0]; bcast[3] = psb[4];
    }
    __syncthreads();
    double Sa = 0.5 * (SAall + (double)bcast[0] - (double)bcast[1]);
    double Sb = 0.5 * (SBall + (double)bcast[2] - (double)bcast[3]);
    if (Sa == 0.0) Sa = 1.0;
    if (Sb == 0.0) Sb = 1.0;
    float invSa = (float)(1.0 / Sa), invSb = (float)(1.0 / Sb);

    float ea = 0.f, eb = 0.f;
#pragma unroll
    for (int k = 0; k < 8; k++) {
        float pa = psa[k] * invSa;
        float pb = psb[k] * invSb;
        ea += pa * __logf(pa + 1e-10f);
        eb += pb * __logf(pb + 1e-10f);
    }
    double EE[2];
    blockReduceSum2((double)ea, (double)eb, sred, EE);
    double EAall = EE[0], EBall = EE[1];

    if (t == 0) {
        float pa0 = psa[0] * invSa, pa4 = psa[4] * invSa;
        float pb0 = psb[0] * invSb, pb4 = psb[4] * invSb;
        double TA = 0.5 * (EAall + (double)(pa0 * __logf(pa0 + 1e-10f))
                                 - (double)(pa4 * __logf(pa4 + 1e-10f)));
        double TB = 0.5 * (EBall + (double)(pb0 * __logf(pb0 + 1e-10f))
                                 - (double)(pb4 * __logf(pb4 + 1e-10f)));
        double mean0 = SUM0 / (double)TT;
        double mean1 = SUM1 / (double)TT;
        double nsq0 = SQ0 - (double)TT * mean0 * mean0; if (nsq0 < 0) nsq0 = 0;
        double nsq1 = SQ1 - (double)TT * mean1 * mean1; if (nsq1 < 0) nsq1 = 0;
        double* w0 = rowstats + (size_t)g0 * 6;
        double* w1 = rowstats + (size_t)g1 * 6;
        double n0 = sqrt(nsq0), n1 = sqrt(nsq1);
        w0[0] = mean0; w0[1] = (n0 == 0.0 ? 1.0 : n0); w0[2] = sqrt(nsq0 / 2047.0);
        w0[3] = SQ0;   w0[4] = MX0;                    w0[5] = -TA;
        w1[0] = mean1; w1[1] = (n1 == 0.0 ? 1.0 : n1); w1[2] = sqrt(nsq1 / 2047.0);
        w1[3] = SQ1;   w1[4] = MX1;                    w1[5] = -TB;
    }
}

// fp32 -> hi/lo bf16 split into LDS staging buffer BUF
#define CVW(BUF, v, row, c4) do { \
    __bf16 _h0 = (__bf16)v.x, _h1 = (__bf16)v.y, _h2 = (__bf16)v.z, _h3 = (__bf16)v.w; \
    __bf16 _l0 = (__bf16)(v.x - (float)_h0), _l1 = (__bf16)(v.y - (float)_h1); \
    __bf16 _l2 = (__bf16)(v.z - (float)_h2), _l3 = (__bf16)(v.w - (float)_h3); \
    *(bf16x4*)&sh_hi[BUF][row][(c4) * 4] = (bf16x4){_h0, _h1, _h2, _h3}; \
    *(bf16x4*)&sh_lo[BUF][row][(c4) * 4] = (bf16x4){_l0, _l1, _l2, _l3}; } while (0)

// load a bf16x8 fragment as two ds_read_b64
#define LDFRAG(dst, arr, BUF, row, ko) do { \
    bf16x4 _f0 = *(const bf16x4*)&arr[BUF][row][ko]; \
    bf16x4 _f1 = *(const bf16x4*)&arr[BUF][row][(ko) + 4]; \
    dst = (bf16x8){_f0[0], _f0[1], _f0[2], _f0[3], _f1[0], _f1[1], _f1[2], _f1[3]}; } while (0)

// ---------- K2: fused per-band gram + finalize (8 waves, in-block K-split) ----------
// One block per band, 512 thr = 8 waves: waves 0-3 and 4-7 form two 2x2 tile
// grids (wave owns 48x48), each handling ONE of the two 32-wide K-slices per
// 64-sample stage. Per wave per stage: 24 ds_read_b64 + 27 MFMA (round-7 had
// 40 + 36 at only 6 waves) -> 35% less serial work per wave AND 2 waves/SIMD.
// After the K-loop, waves 4-7 dump their partial tile into Cs (exactly 96x96)
// and waves 0-3 merge - no global traffic, no extra LDS. Epilogue unchanged.
__global__ __launch_bounds__(FBLK) void fused_gram_finalize_kernel(
    const float* __restrict__ wc, const double* __restrict__ rowstats,
    const int* __restrict__ community,
    const float* __restrict__ W1, const float* __restrict__ b1,
    const float* __restrict__ W2, const float* __restrict__ b2,
    float* __restrict__ A_out, float* __restrict__ F_out)
{
    __shared__ __attribute__((aligned(16))) __bf16 sh_hi[2][RR][GPITCH]; // 29.2 KB
    __shared__ __attribute__((aligned(16))) __bf16 sh_lo[2][RR][GPITCH]; // 29.2 KB
    __shared__ float Cs[RR][RR];               // 36 KB
    __shared__ int hist[NBIN];                 // 32 KB
    __shared__ int chunkv[256];
    __shared__ int pchunk[256];
    __shared__ int gpre_s[64];
    __shared__ float cand[MAXCAND];
    __shared__ int ctrl[8];
    __shared__ float selv[2];
    __shared__ double mean_s[RR], inv_s[RR];
    __shared__ int comm_s[RR];
    __shared__ unsigned long long msk[RR][2];
    __shared__ int deg[RR];
    __shared__ double sred[40];
    __shared__ double feat[11];
    __shared__ double hmlp[32];
    __shared__ double thr_s;

    int band = blockIdx.x, t = threadIdx.x;
    int b = band / 5, nb = band % 5;
    size_t bandbase = ((size_t)b * RR * 5 + nb) * TT;
    const double* rsb = rowstats + (size_t)band * RR * 6;

    if (t < RR) {
        mean_s[t] = rsb[t * 6 + 0];
        inv_s[t]  = 1.0 / rsb[t * 6 + 1];
        comm_s[t] = community[t];
    }
    for (int i = t; i < NBIN; i += FBLK) hist[i] = 0;
    if (t == 0) ctrl[3] = 0;

    int wave = t >> 6, lane = t & 63;
    int m16 = lane & 15, quad = lane >> 4;
    int kw = wave >> 2;          // 0..1  (K half of each 64-stage)
    int wq = wave & 3;           // 0..3  (tile quadrant)
    int wr = wq >> 1;            // 0..1  (row block of 48)
    int wcx = wq & 1;            // 0..1  (col block of 48)

    // per-thread staging slots: gid = t + i*512 over 1536 = 96 rows x 16 float4
    int row0 = t >> 4,           c40 = t & 15;
    int row1 = (t + 512) >> 4,   c41 = (t + 512) & 15;
    int row2 = (t + 1024) >> 4,  c42 = (t + 1024) & 15;
    const float* p0 = wc + bandbase + (size_t)row0 * (5 * TT) + c40 * 4;
    const float* p1 = wc + bandbase + (size_t)row1 * (5 * TT) + c41 * 4;
    const float* p2 = wc + bandbase + (size_t)row2 * (5 * TT) + c42 * 4;

    f32x4 acc[3][3];
#pragma unroll
    for (int rs = 0; rs < 3; rs++)
#pragma unroll
        for (int cs = 0; cs < 3; cs++) acc[rs][cs] = (f32x4){0.f, 0.f, 0.f, 0.f};

    // prologue: stage 0 into buffer 0
    {
        float4 v0 = *(const float4*)(p0);
        float4 v1 = *(const float4*)(p1);
        float4 v2 = *(const float4*)(p2);
        CVW(0, v0, row0, c40); CVW(0, v1, row1, c41); CVW(0, v2, row2, c42);
    }
    __syncthreads();

    for (int st = 0; st < NST; st++) {
        int cur = st & 1;
        float4 q0, q1, q2;
        bool more = (st + 1 < NST);
        if (more) {
            int k0 = (st + 1) * BKS;
            q0 = *(const float4*)(p0 + k0);
            q1 = *(const float4*)(p1 + k0);
            q2 = *(const float4*)(p2 + k0);
        }
        {
            int ko = kw * 32 + quad * 8;     // this wave's K slice
            bf16x8 ah[3], al[3];
#pragma unroll
            for (int rs = 0; rs < 3; rs++) {
                int ar = wr * 48 + rs * 16 + m16;
                LDFRAG(ah[rs], sh_hi, cur, ar, ko);
                LDFRAG(al[rs], sh_lo, cur, ar, ko);
            }
#pragma unroll
            for (int cs = 0; cs < 3; cs++) {
                int br = wcx * 48 + cs * 16 + m16;
                bf16x8 bh, bl;
                LDFRAG(bh, sh_hi, cur, br, ko);
                LDFRAG(bl, sh_lo, cur, br, ko);
#pragma unroll
                for (int rs = 0; rs < 3; rs++) {
                    acc[rs][cs] = __builtin_amdgcn_mfma_f32_16x16x32_bf16(ah[rs], bh, acc[rs][cs], 0, 0, 0);
                    acc[rs][cs] = __builtin_amdgcn_mfma_f32_16x16x32_bf16(ah[rs], bl, acc[rs][cs], 0, 0, 0);
                    acc[rs][cs] = __builtin_amdgcn_mfma_f32_16x16x32_bf16(al[rs], bh, acc[rs][cs], 0, 0, 0);
                }
            }
        }
        if (more) {
            int nxt = cur ^ 1;
            CVW(nxt, q0, row0, c40); CVW(nxt, q1, row1, c41); CVW(nxt, q2, row2, c42);
        }
        __syncthreads();
    }

    // merge the two K-halves: waves 4-7 dump their tiles into Cs (the 4 tiles
    // of 4 waves x 64 lanes x 36 values cover 96x96 exactly), waves 0-3 add.
    if (kw == 1) {
#pragma unroll
        for (int rs = 0; rs < 3; rs++)
#pragma unroll
            for (int cs = 0; cs < 3; cs++)
#pragma unroll
                for (int r = 0; r < 4; r++) {
                    int grow = wr * 48 + rs * 16 + quad * 4 + r;
                    int gcol = wcx * 48 + cs * 16 + m16;
                    Cs[grow][gcol] = acc[rs][cs][r];
                }
    }
    __syncthreads();
    if (kw == 0) {
#pragma unroll
        for (int rs = 0; rs < 3; rs++)
#pragma unroll
            for (int cs = 0; cs < 3; cs++)
#pragma unroll
                for (int r = 0; r < 4; r++) {
                    int grow = wr * 48 + rs * 16 + quad * 4 + r;
                    int gcol = wcx * 48 + cs * 16 + m16;
                    acc[rs][cs][r] += Cs[grow][gcol];
                }
    }
    __syncthreads();   // Cs reads done; safe to overwrite

    // epilogue: normalize in-register (waves 0-3 own the full matrix),
    // write Cs, histogram tril on the fly
    if (kw == 0) {
#pragma unroll
        for (int rs = 0; rs < 3; rs++) {
#pragma unroll
            for (int cs = 0; cs < 3; cs++) {
#pragma unroll
                for (int r = 0; r < 4; r++) {
                    int grow = wr * 48 + rs * 16 + quad * 4 + r;
                    int gcol = wcx * 48 + cs * 16 + m16;
                    double cd = ((double)acc[rs][cs][r]
                                 - (double)TT * mean_s[grow] * mean_s[gcol])
                                * (inv_s[grow] * inv_s[gcol]);
                    if (grow == gcol) cd = 0.0;
                    float cf = (float)cd;
                    Cs[grow][gcol] = cf;
                    if (gcol < grow) {
                        float val = fabsf(cf);
                        int bin = (int)(val * (float)NBIN);
                        bin = bin > (NBIN - 1) ? (NBIN - 1) : bin;
                        atomicAdd(&hist[bin], 1);
                    }
                }
            }
        }
    }
    __syncthreads();

    // ---- parallel quantile select: ranks R0=3647, R1=3648 ----
    if (t < 256) {
        int cs = 0;
#pragma unroll
        for (int i = 0; i < NBIN / 256; i++) cs += hist[t * (NBIN / 256) + i];
        chunkv[t] = cs;
    }
    __syncthreads();
    if (t < 64) {
        int s4 = chunkv[4 * t] + chunkv[4 * t + 1] + chunkv[4 * t + 2] + chunkv[4 * t + 3];
        int inc = s4;
        for (int d = 1; d < 64; d <<= 1) {
            int u = __shfl_up(inc, d, 64);
            if (t >= d) inc += u;
        }
        gpre_s[t] = inc - s4;               // exclusive prefix of 4-chunk groups
    }
    __syncthreads();
    if (t < 256) {
        int base = gpre_s[t >> 2];
        for (int j = (t & ~3); j < t; j++) base += chunkv[j];
        pchunk[t] = base;                    // exclusive prefix of chunk t
    }
    __syncthreads();
    if (t < 256) {
        int lo = pchunk[t], hi2 = lo + chunkv[t];
        if (lo <= 3647 && 3647 < hi2) ctrl[4] = t;
        if (lo <= 3648 && 3648 < hi2) ctrl[5] = t;
    }
    __syncthreads();
    {
        int c0 = ctrl[4], c1 = ctrl[5];
        if (t < 32) {
            int binb = c0 * 32;
            int pre = pchunk[c0];
            for (int j = 0; j < t; j++) pre += hist[binb + j];
            int cnt = hist[binb + t];
            if (pre <= 3647 && 3647 < pre + cnt) { ctrl[0] = binb + t; ctrl[2] = pre; }
        } else if (t < 64) {
            int tt2 = t - 32;
            int binb = c1 * 32;
            int pre = pchunk[c1];
            for (int j = 0; j < tt2; j++) pre += hist[binb + j];
            int cnt = hist[binb + tt2];
            if (pre <= 3648 && 3648 < pre + cnt) ctrl[1] = binb + tt2;
        }
    }
    __syncthreads();

    int B0 = ctrl[0], B1 = ctrl[1];
    for (int idx = t; idx < RR * RR; idx += FBLK) {
        int i = idx / RR, j = idx % RR;
        if (j < i) {
            float val = fabsf(Cs[i][j]);
            int bin = (int)(val * (float)NBIN);
            bin = bin > (NBIN - 1) ? (NBIN - 1) : bin;
            if (bin >= B0 && bin <= B1) {
                int k = atomicAdd(&ctrl[3], 1);
                if (k < MAXCAND) cand[k] = val;
            }
        }
    }
    __syncthreads();

    // parallel rank selection (unique total order via (value, index) tie-break)
    {
        int n = ctrl[3]; if (n > MAXCAND) n = MAXCAND;
        int r0l = 3647 - ctrl[2];
        int r1l = 3648 - ctrl[2];
        for (int i = t; i < n; i += FBLK) {
            float v = cand[i];
            int rank = 0;
            for (int j = 0; j < n; j++) {
                float u = cand[j];
                rank += (u < v || (u == v && j < i)) ? 1 : 0;
            }
            if (rank == r0l) selv[0] = v;
            if (rank == r1l) selv[1] = v;
        }
    }
    __syncthreads();
    if (t == 0) {
        double v0 = (double)selv[0], v1 = (double)selv[1];
        thr_s = v0 + 0.2 * (v1 - v0);       // pos = 0.8*(4560-1) = 3647.2
    }
    __syncthreads();
    double thr = thr_s;

    // masked A write (single pass, coalesced)
    float* Ab = A_out + (size_t)band * (RR * RR);
    for (int idx = t; idx < RR * RR; idx += FBLK) {
        float cf = Cs[idx / RR][idx % RR];
        bool keep = ((double)fabsf(cf) >= thr);
        Ab[idx] = keep ? cf : 0.f;
    }

    // adjacency bitmasks via ballot: wave w handles rows w, w+8, ...
    for (int i = wave; i < RR; i += 8) {
        float vlo = Cs[i][lane];
        bool klo = ((double)fabsf(vlo) >= thr) && (vlo != 0.f);
        unsigned long long blo = __ballot(klo);
        float vhi = Cs[i][64 + (lane & 31)];
        bool khi = (lane < 32) && ((double)fabsf(vhi) >= thr) && (vhi != 0.f);
        unsigned long long bhi = __ballot(khi) & 0xffffffffull;
        if (lane == 0) {
            msk[i][0] = blo; msk[i][1] = bhi;
            deg[i] = __popcll(blo) + __popcll(bhi);
        }
    }
    __syncthreads();

    double triord = 0, ein = 0, expin = 0;
    for (int idx = t; idx < RR * RR; idx += FBLK) {
        int i = idx / RR, j = idx % RR;
        unsigned long long mi0 = msk[i][0], mi1 = msk[i][1];
        bool bij = (((j < 64) ? (mi0 >> j) : (mi1 >> (j - 64))) & 1ull) != 0;
        if (bij)
            triord += (double)(__popcll(mi0 & msk[j][0]) +
                               __popcll(mi1 & msk[j][1]));
        if (i != j && comm_s[i] == comm_s[j]) {
            ein += bij ? 1.0 : 0.0;
            expin += (double)deg[i] * (double)deg[j];
        }
    }
    double dv = (t < RR) ? (double)deg[t] : 0.0;
    double R1v[4], R2v[4], R3v[2];
    blockReduceSum4(triord, ein, expin, dv, sred, R1v);
    blockReduceSum4((t < RR) ? dv * (dv - 1.0) : 0.0,
                    (t < RR) ? rsb[t * 6 + 0] : 0.0,
                    (t < RR) ? rsb[t * 6 + 2] : 0.0,
                    (t < RR) ? rsb[t * 6 + 3] : 0.0, sred, R2v);
    blockReduceSum2((t < RR) ? rsb[t * 6 + 4] : 0.0,
                    (t < RR) ? rsb[t * 6 + 5] : 0.0, sred, R3v);
    double TRI = R1v[0], EIN = R1v[1], EXPIN = R1v[2], DEGS = R1v[3];
    double POSS2 = R2v[0], N0 = R2v[1], N1 = R2v[2], N2 = R2v[3];
    double N3 = R3v[0], N4 = R3v[1];

    if (t == 0) {
        double ne = 0.5 * DEGS;
        feat[0] = N0 / (double)RR;
        feat[1] = N1 / (double)RR;
        feat[2] = N2 / (double)RR;
        feat[3] = N3 / (double)RR;
        feat[4] = N4 / (double)RR;
        feat[5] = ne;
        feat[6] = ne / (double)NTRIL;
        feat[7] = DEGS / (double)RR;
        double tri = TRI / 6.0, poss = POSS2 * 0.5;
        feat[8] = (poss > 0.0) ? tri / poss : 0.0;
        feat[9] = ((double)RR + DEGS) / ((double)RR * (double)(RR - 1));
        double m2 = DEGS;
        feat[10] = (m2 > 0.0) ? (EIN - EXPIN / m2) / m2 : 0.0;
    }
    __syncthreads();

    if (t < 32) {
        double a = (double)b1[t];
        for (int k = 0; k < 11; k++) a += (double)W1[t * 11 + k] * feat[k];
        hmlp[t] = (a > 0.0) ? a : 0.0;
    }
    __syncthreads();
    if (t < 64) {
        double a = (double)b2[t];
        for (int j = 0; j < 32; j++) a += (double)W2[t * 32 + j] * hmlp[j];
        F_out[(size_t)band * 64 + t] = (float)a;
    }
}

extern "C" void kernel_launch(void* const* d_in, const int* in_sizes, int n_in,
                              void* d_out, int out_size, void* d_ws, size_t ws_size,
                              hipStream_t stream) {
    const float* wc        = (const float*)d_in[0];
    // d_in[1] frequency_bands: unused by the reference math
    const int*   community = (const int*)d_in[2];
    const float* W1        = (const float*)d_in[3];
    const float* b1        = (const float*)d_in[4];
    const float* W2        = (const float*)d_in[5];
    const float* b2        = (const float*)d_in[6];

    float* A_out = (float*)d_out;
    float* F_out = A_out + A_ELEMS;

    // workspace layout: tw @ 0 (8192 B) | rowstats @ 8192 (15360*6*8 = 737280 B)
    char* ws = (char*)d_ws;
    float*  tw       = (float*)ws;
    double* rowstats = (double*)(ws + 8192);

    hipLaunchKernelGGL(twiddle_kernel, dim3(4), dim3(256), 0, stream, tw);
    hipLaunchKernelGGL(rowstat_fft_kernel, dim3(NBANDS * RR / 2), dim3(256), 0, stream,
                       wc, tw, rowstats);
    hipLaunchKernelGGL(fused_gram_finalize_kernel, dim3(NBANDS), dim3(FBLK), 0, stream,
                       wc, rowstats, community, W1, b1, W2, b2, A_out, F_out);
}